// Round 20
// baseline (276.073 us; speedup 1.0000x reference)
//
#include <hip/hip_runtime.h>
#include <hip/hip_bf16.h>

// Flash-attention fwd, fp32 in/out, bf16 MFMA compute.
// B=64, L=1024, D=64. scale=1/sqrt(512). mask(int32)!=0 -> -1e9.
// R20 = R19 zero-barrier design with both confounds fixed:
//  - V staging uses R16's PROVEN 2-way-free bank pattern, per-wave:
//    lane (c,gg) writes vt[(gg*4+dd*16)+jj][(c)*4] (rotated jj) — banks
//    2c+16(gg&1), 2 lanes/bank = free. (R19's pattern was 8-way.)
//  - Phased register lifetimes: kf loaded per-f in the QK^T loop; V loaded
//    in 2 chunks of 8 f32x4, cvt+written right after QK^T (regs die before
//    softmax). Peak ~126 VGPR < (256,3) cap ~170 — no scratch.
//  - ZERO __syncthreads: waves fully independent (clean barrier-convoy test)
//  - kept: XCD decode, 2-deep mask ring, mask-as-C-seed, invT pre-folded,
//    wave-private p_lds P relayout.

typedef __attribute__((ext_vector_type(4))) float f32x4;
typedef __attribute__((ext_vector_type(8))) short bf16x8;
typedef __attribute__((ext_vector_type(4))) short short4v;

constexpr int B_ = 64;
constexpr int L_ = 1024;
constexpr int D_ = 64;
constexpr int QBLK = 64;     // q rows per block (4 waves x 16)
constexpr int KV = 64;       // keys per tile
constexpr int NKV = L_ / KV; // 16 tiles
constexpr int STR = 72;      // shorts per LDS row (64 + 8 pad)
constexpr float INV_TEMP = 0.04419417382415922f; // 1/sqrt(512)
constexpr float NEG = -1e9f;

__device__ inline short f2bf(float f) {
  __hip_bfloat16 h = __float2bfloat16(f);
  short s; __builtin_memcpy(&s, &h, 2);
  return s;
}

__global__ __launch_bounds__(256, 3) void attn_fwd(
    const float* __restrict__ Q, const float* __restrict__ K,
    const float* __restrict__ V, const int* __restrict__ M,
    float* __restrict__ O)
{
  __shared__ short vt_lds[4][D_][STR];  // 36.9 KB, one quarter per wave
  __shared__ short p_lds[4][16][STR];   //  9.2 KB  -> 46.1 KB, 3 blocks/CU

  const int tid  = threadIdx.x;
  const int w    = tid >> 6;
  const int lane = tid & 63;
  const int g    = lane >> 4;
  const int c    = lane & 15;

  // ---- XCD-aware decode: all 16 q-tile blocks of batch b on one XCD
  const int p   = blockIdx.x;
  const int xcd = p & 7;
  const int j   = p >> 3;           // 0..127
  const int b   = xcd + 8 * (j >> 4);
  const int q0  = (j & 15) * QBLK;

  short (*vt)[STR] = vt_lds[w];     // this wave's private V^T quarter
  short (*pl)[STR] = p_lds[w];      // this wave's private P buffer

  // ---- Q fragment (B operand of swapped QK^T), invT pre-folded
  bf16x8 qf[2];
  {
    const float* qp = Q + ((size_t)b * L_ + q0 + w * 16 + c) * D_ + g * 8;
#pragma unroll
    for (int ks = 0; ks < 2; ++ks) {
      f32x4 x0 = *(const f32x4*)(qp + ks * 32);
      f32x4 x1 = *(const f32x4*)(qp + ks * 32 + 4);
      bf16x8 t;
      t[0] = f2bf(x0[0] * INV_TEMP); t[1] = f2bf(x0[1] * INV_TEMP);
      t[2] = f2bf(x0[2] * INV_TEMP); t[3] = f2bf(x0[3] * INV_TEMP);
      t[4] = f2bf(x1[0] * INV_TEMP); t[5] = f2bf(x1[1] * INV_TEMP);
      t[6] = f2bf(x1[2] * INV_TEMP); t[7] = f2bf(x1[3] * INV_TEMP);
      qf[ks] = t;
    }
  }

  const float* Kb = K + (size_t)b * L_ * D_;
  const float* Vb = V + (size_t)b * L_ * D_;
  // mask, swapped layout: lane's own row q=w*16+c, keys f*16+4g+0..3 per tile
  const int* mlane = M + (size_t)b * L_ * L_ + (size_t)(q0 + w * 16 + c) * L_ + 4 * g;

  int4 mA[4], mB[4];                 // mask ring, 2 tiles deep
  auto load_m = [&](int t, int4 (&mr)[4]) {
#pragma unroll
    for (int f = 0; f < 4; ++f) mr[f] = *(const int4*)(mlane + t * KV + f * 16);
  };

  // V staging geometry (per wave, R16's bank-free pattern): lane covers
  // keys vkey4..vkey4+3, d rows vd4+dd*16 (dd=0..3)
  const int vkey4 = c * 4;
  const int vd4   = g * 4;

  f32x4 acc[4];
#pragma unroll
  for (int i = 0; i < 4; ++i) acc[i] = (f32x4){0.f, 0.f, 0.f, 0.f};
  float m_run = -INFINITY;  // per-lane, q-row = w*16+c
  float l_run = 0.f;

  load_m(0, mA);
  load_m(1, mB);

  auto body = [&](int t, int4 (&mbuf)[4], bool refill) {
    int4 mc[4];
#pragma unroll
    for (int f = 0; f < 4; ++f) mc[f] = mbuf[f];   // consume (reg moves)
    if (refill) load_m(t + 2, mbuf);               // refill: 2-deep ring

    // ---- S^T = K (Q*invT)^T + mask-bias seed; K DIRECT from global in
    //      A-layout (row=key=f*16+c, k=ks*32+g*8+j; L2-hot via XCD swizzle).
    //      kf transient per-f (compiler hoists load batches as regs allow).
    f32x4 sc[4];
#pragma unroll
    for (int f = 0; f < 4; ++f) {
      const float* kp = Kb + (size_t)(t * KV + f * 16 + c) * D_ + g * 8;
      f32x4 ka0 = *(const f32x4*)(kp);
      f32x4 ka1 = *(const f32x4*)(kp + 4);
      f32x4 kb0 = *(const f32x4*)(kp + 32);
      f32x4 kb1 = *(const f32x4*)(kp + 36);
      bf16x8 kf0, kf1;
      kf0[0] = f2bf(ka0[0]); kf0[1] = f2bf(ka0[1]); kf0[2] = f2bf(ka0[2]); kf0[3] = f2bf(ka0[3]);
      kf0[4] = f2bf(ka1[0]); kf0[5] = f2bf(ka1[1]); kf0[6] = f2bf(ka1[2]); kf0[7] = f2bf(ka1[3]);
      kf1[0] = f2bf(kb0[0]); kf1[1] = f2bf(kb0[1]); kf1[2] = f2bf(kb0[2]); kf1[3] = f2bf(kb0[3]);
      kf1[4] = f2bf(kb1[0]); kf1[5] = f2bf(kb1[1]); kf1[6] = f2bf(kb1[2]); kf1[7] = f2bf(kb1[3]);
      f32x4 a;
      a[0] = mc[f].x ? NEG : 0.0f;
      a[1] = mc[f].y ? NEG : 0.0f;
      a[2] = mc[f].z ? NEG : 0.0f;
      a[3] = mc[f].w ? NEG : 0.0f;
      a = __builtin_amdgcn_mfma_f32_16x16x32_bf16(kf0, qf[0], a, 0, 0, 0);
      a = __builtin_amdgcn_mfma_f32_16x16x32_bf16(kf1, qf[1], a, 0, 0, 0);
      sc[f] = a;
    }

    // ---- V stage to own quarter, 2 chunks of 8 f32x4 (regs die here).
    //      R16's bank-free pattern: write vt[vd4+dd*16+jj][vkey4], jj rotated.
#pragma unroll
    for (int half = 0; half < 2; ++half) {
      f32x4 vr[2][4];
#pragma unroll
      for (int dd2 = 0; dd2 < 2; ++dd2)
#pragma unroll
        for (int i = 0; i < 4; ++i)
          vr[dd2][i] = *(const f32x4*)(Vb + (size_t)(t * KV + vkey4 + i) * D_
                                       + vd4 + (half * 2 + dd2) * 16);
#pragma unroll
      for (int dd2 = 0; dd2 < 2; ++dd2) {
        const int drow = vd4 + (half * 2 + dd2) * 16;
#pragma unroll
        for (int jj0 = 0; jj0 < 4; ++jj0) {
          const int jj = (jj0 + g) & 3;    // rotated row order (bank spread)
          short4v vt4 = { f2bf(vr[dd2][0][jj]), f2bf(vr[dd2][1][jj]),
                          f2bf(vr[dd2][2][jj]), f2bf(vr[dd2][3][jj]) };
          *(short4v*)&vt[drow + jj][vkey4] = vt4;
        }
      }
    }

    // ---- online softmax, per-lane row (16 in-lane keys x 4 lane-groups)
    float x = sc[0][0];
#pragma unroll
    for (int f = 0; f < 4; ++f)
#pragma unroll
      for (int r = 0; r < 4; ++r) x = fmaxf(x, sc[f][r]);
    x = fmaxf(x, __shfl_xor(x, 16, 64));
    x = fmaxf(x, __shfl_xor(x, 32, 64));
    const float m_new = fmaxf(m_run, x);
    const float alpha = __expf(m_run - m_new);
    float s = 0.f;
#pragma unroll
    for (int f = 0; f < 4; ++f)
#pragma unroll
      for (int r = 0; r < 4; ++r) {
        sc[f][r] = __expf(sc[f][r] - m_new);
        s += sc[f][r];
      }
    s += __shfl_xor(s, 16, 64);
    s += __shfl_xor(s, 32, 64);
    l_run = l_run * alpha + s;
    m_run = m_new;

    // ---- rescale acc: acc rows are q=g*4+r -> alpha from lane c'=g*4+r
    float ar[4];
#pragma unroll
    for (int r = 0; r < 4; ++r)
      ar[r] = __shfl(alpha, (lane & 48) | (g * 4 + r), 64);
#pragma unroll
    for (int fd = 0; fd < 4; ++fd)
#pragma unroll
      for (int r = 0; r < 4; ++r) acc[fd][r] *= ar[r];

    // ---- P -> wave-private LDS: lane owns P[q=c][keys f*16+4g+0..3]
#pragma unroll
    for (int f = 0; f < 4; ++f) {
      short4v pk = { f2bf(sc[f][0]), f2bf(sc[f][1]),
                     f2bf(sc[f][2]), f2bf(sc[f][3]) };
      *(short4v*)&pl[c][f * 16 + 4 * g] = pk;
    }

    // ---- O += P V (reads own quarter; same-wave DS in-order, no barrier)
#pragma unroll
    for (int ks = 0; ks < 2; ++ks) {
      bf16x8 pa = *(const bf16x8*)&pl[c][ks * 32 + g * 8];
#pragma unroll
      for (int fd = 0; fd < 4; ++fd) {
        bf16x8 vb = *(const bf16x8*)&vt[fd * 16 + c][ks * 32 + g * 8];
        acc[fd] = __builtin_amdgcn_mfma_f32_16x16x32_bf16(pa, vb, acc[fd], 0, 0, 0);
      }
    }
    // NO barrier anywhere: per-wave DS pipe orders next tile's writes
    // after this tile's reads.
  };

  for (int tt = 0; tt < NKV; tt += 2) {
    body(tt,     mA, tt + 2 < NKV);   // consume m(tt),   refill -> m(tt+2)
    body(tt + 1, mB, tt + 3 < NKV);   // consume m(tt+1), refill -> m(tt+3)
  }

  // ---- epilogue: acc[fd][r] = O[q=g*4+r][d=fd*16+c]; l lives at lane c'=q
  const float li = 1.0f / l_run;
  float lr[4];
#pragma unroll
  for (int r = 0; r < 4; ++r)
    lr[r] = __shfl(li, (lane & 48) | (g * 4 + r), 64);
  float* orow = O + ((size_t)b * L_ + q0 + w * 16 + g * 4) * D_;
#pragma unroll
  for (int fd = 0; fd < 4; ++fd)
#pragma unroll
    for (int r = 0; r < 4; ++r)
      orow[(size_t)r * D_ + fd * 16 + c] = acc[fd][r] * lr[r];
}

extern "C" void kernel_launch(void* const* d_in, const int* in_sizes, int n_in,
                              void* d_out, int out_size, void* d_ws, size_t ws_size,
                              hipStream_t stream) {
  const float* q = (const float*)d_in[0];
  const float* k = (const float*)d_in[1];
  const float* v = (const float*)d_in[2];
  const int* m = (const int*)d_in[3]; // jax bool shipped as int32
  float* o = (float*)d_out;
  attn_fwd<<<dim3(1024), 256, 0, stream>>>(q, k, v, m, o);
}

// Round 21
// 116.407 us; speedup vs baseline: 2.3716x; 2.3716x over previous
//
#include <hip/hip_runtime.h>
#include <hip/hip_bf16.h>

// Flash-attention fwd, fp32 in/out, bf16 MFMA compute.
// B=64, L=1024, D=64. scale=1/sqrt(512). mask(int32)!=0 -> -1e9.
// R21 = R16 core with QBLK=128: 8 waves (512 thr) share ONE K/V staging.
//  - Role-split staging (wave-uniform): threads 0-255 stage K (R16 pattern),
//    threads 256-511 stage V (R16's proven 2-way-free transpose pattern).
//    Per-output staging cost and K/V HBM traffic HALVE vs R16.
//  - Held prefetch halves per thread (K or V, 16 VGPR) -> fits (512,4) cap.
//  - LDS 55.3 KB -> 2 blocks/CU = 16 waves/CU (vs R16's 12).
//  - Per-wave core byte-identical to R16: swapped QK^T, mask-as-C-seed,
//    invT-prefolded Q, plain softmax, p_lds PV path, 2-deep mask ring,
//    dbuf one-barrier tiles, XCD-aware decode.

typedef __attribute__((ext_vector_type(4))) float f32x4;
typedef __attribute__((ext_vector_type(8))) short bf16x8;
typedef __attribute__((ext_vector_type(4))) short short4v;

constexpr int B_ = 64;
constexpr int L_ = 1024;
constexpr int D_ = 64;
constexpr int QBLK = 128;    // q rows per block (8 waves x 16)
constexpr int KV = 64;       // keys per tile
constexpr int NKV = L_ / KV; // 16 tiles
constexpr int STR = 72;      // shorts per LDS row (64 + 8 pad)
constexpr float INV_TEMP = 0.04419417382415922f; // 1/sqrt(512)
constexpr float NEG = -1e9f;

__device__ inline short f2bf(float f) {
  __hip_bfloat16 h = __float2bfloat16(f);
  short s; __builtin_memcpy(&s, &h, 2);
  return s;
}

__global__ __launch_bounds__(512, 4) void attn_fwd(
    const float* __restrict__ Q, const float* __restrict__ K,
    const float* __restrict__ V, const int* __restrict__ M,
    float* __restrict__ O)
{
  __shared__ short k_lds[2][KV][STR];   // 18.4 KB
  __shared__ short vt_lds[2][D_][STR];  // 18.4 KB
  __shared__ short p_lds[8][16][STR];   // 18.4 KB -> 55.3 KB, 2 blocks/CU

  const int tid  = threadIdx.x;
  const int w    = tid >> 6;        // 0..7, wave owns q-rows w*16..w*16+15
  const int lane = tid & 63;
  const int g    = lane >> 4;
  const int c    = lane & 15;

  // ---- XCD-aware decode: all 8 q-tile blocks of batch b on one XCD
  const int p   = blockIdx.x;       // 512 blocks
  const int xcd = p & 7;
  const int j   = p >> 3;           // 0..63
  const int b   = xcd + 8 * (j >> 3);
  const int q0  = (j & 7) * QBLK;

  // ---- Q fragment (B operand of swapped QK^T), invT pre-folded
  bf16x8 qf[2];
  {
    const float* qp = Q + ((size_t)b * L_ + q0 + w * 16 + c) * D_ + g * 8;
#pragma unroll
    for (int ks = 0; ks < 2; ++ks) {
      f32x4 x0 = *(const f32x4*)(qp + ks * 32);
      f32x4 x1 = *(const f32x4*)(qp + ks * 32 + 4);
      bf16x8 t;
      t[0] = f2bf(x0[0] * INV_TEMP); t[1] = f2bf(x0[1] * INV_TEMP);
      t[2] = f2bf(x0[2] * INV_TEMP); t[3] = f2bf(x0[3] * INV_TEMP);
      t[4] = f2bf(x1[0] * INV_TEMP); t[5] = f2bf(x1[1] * INV_TEMP);
      t[6] = f2bf(x1[2] * INV_TEMP); t[7] = f2bf(x1[3] * INV_TEMP);
      qf[ks] = t;
    }
  }

  const float* Kb = K + (size_t)b * L_ * D_;
  const float* Vb = V + (size_t)b * L_ * D_;
  // mask, swapped layout: lane's own row q=w*16+c, keys f*16+4g+0..3 per tile
  const int* mlane = M + (size_t)b * L_ * L_ + (size_t)(q0 + w * 16 + c) * L_ + 4 * g;

  // ---- role-split staging: waves 0-3 stage K, waves 4-7 stage V
  const bool kstager = (tid < 256);
  const int  htid    = tid & 255;
  const int  vkey4   = (htid & 15) * 4;   // V stager: 4x4 block per thread
  const int  vd4     = (htid >> 4) * 4;

  f32x4 sreg[4];                      // HELD: K rows (kstager) or V block
  int4  mA[4], mB[4];                 // mask ring, 2 tiles deep

  auto load_kv = [&](int t) {
    if (kstager) {
      const float* ksrc = Kb + (size_t)(t * KV) * D_;
#pragma unroll
      for (int i = 0; i < 4; ++i)
        sreg[i] = *(const f32x4*)(ksrc + (size_t)(htid + i * 256) * 4);
    } else {
      const float* vsrc = Vb + (size_t)(t * KV) * D_;
#pragma unroll
      for (int i = 0; i < 4; ++i)
        sreg[i] = *(const f32x4*)(vsrc + (size_t)(vkey4 + i) * D_ + vd4);
    }
  };
  auto load_m = [&](int t, int4 (&mr)[4]) {
#pragma unroll
    for (int f = 0; f < 4; ++f) mr[f] = *(const int4*)(mlane + t * KV + f * 16);
  };
  auto write_kv = [&](int buf) {      // cvt + ds_write from held regs
    if (kstager) {
#pragma unroll
      for (int i = 0; i < 4; ++i) {
        const int idx = htid + i * 256;
        short4v ks4 = { f2bf(sreg[i][0]), f2bf(sreg[i][1]),
                        f2bf(sreg[i][2]), f2bf(sreg[i][3]) };
        *(short4v*)&k_lds[buf][idx >> 4][(idx & 15) * 4] = ks4;
      }
    } else {
#pragma unroll
      for (int i = 0; i < 4; ++i) {
        const int jj = (i + (htid >> 4)) & 3; // rotated row order (bank spread)
        short4v vt4 = { f2bf(sreg[0][jj]), f2bf(sreg[1][jj]),
                        f2bf(sreg[2][jj]), f2bf(sreg[3][jj]) };
        *(short4v*)&vt_lds[buf][vd4 + jj][vkey4] = vt4;
      }
    }
  };

  f32x4 acc[4];
#pragma unroll
  for (int i = 0; i < 4; ++i) acc[i] = (f32x4){0.f, 0.f, 0.f, 0.f};
  float m_run = -INFINITY;  // per-lane, q-row = w*16+c
  float l_run = 0.f;

  // prologue: tile 0 staged; masks for tiles 0,1 in flight (2-deep)
  load_kv(0);
  write_kv(0);
  load_m(0, mA);
  load_m(1, mB);
  __syncthreads();

  auto body = [&](int t, int4 (&mbuf)[4], bool refill) {
    const int cur = t & 1;
    const bool has_next = (t + 1 < NKV);
    if (has_next) load_kv(t + 1);      // issue early, HELD through compute
    int4 mc[4];
#pragma unroll
    for (int f = 0; f < 4; ++f) mc[f] = mbuf[f];   // consume (reg moves)
    if (refill) load_m(t + 2, mbuf);   // refill same buffer: 2-deep ring
    __builtin_amdgcn_sched_barrier(0); // PIN: loads stay above compute

    // ---- mask bias as MFMA C-seed (fills the lgkmcnt wait shadow)
    f32x4 sc[4];
#pragma unroll
    for (int f = 0; f < 4; ++f) {
      sc[f][0] = mc[f].x ? NEG : 0.0f;
      sc[f][1] = mc[f].y ? NEG : 0.0f;
      sc[f][2] = mc[f].z ? NEG : 0.0f;
      sc[f][3] = mc[f].w ? NEG : 0.0f;
    }

    // ---- S^T = K (Q*invT)^T + bias : C row = key = f*16+g*4+r, col = q = c
#pragma unroll
    for (int f = 0; f < 4; ++f) {
      f32x4 a = sc[f];
#pragma unroll
      for (int ks = 0; ks < 2; ++ks) {
        bf16x8 kf = *(const bf16x8*)&k_lds[cur][f * 16 + c][ks * 32 + g * 8];
        a = __builtin_amdgcn_mfma_f32_16x16x32_bf16(kf, qf[ks], a, 0, 0, 0);
      }
      sc[f] = a;
    }

    // ---- online softmax, per-lane row (16 in-lane keys x 4 lane-groups)
    float x = sc[0][0];
#pragma unroll
    for (int f = 0; f < 4; ++f)
#pragma unroll
      for (int r = 0; r < 4; ++r) x = fmaxf(x, sc[f][r]);
    x = fmaxf(x, __shfl_xor(x, 16, 64));
    x = fmaxf(x, __shfl_xor(x, 32, 64));
    const float m_new = fmaxf(m_run, x);
    const float alpha = __expf(m_run - m_new);
    float s = 0.f;
#pragma unroll
    for (int f = 0; f < 4; ++f)
#pragma unroll
      for (int r = 0; r < 4; ++r) {
        sc[f][r] = __expf(sc[f][r] - m_new);
        s += sc[f][r];
      }
    s += __shfl_xor(s, 16, 64);
    s += __shfl_xor(s, 32, 64);
    l_run = l_run * alpha + s;
    m_run = m_new;

    // ---- rescale acc: acc rows are q=g*4+r -> alpha from lane c'=g*4+r
    float ar[4];
#pragma unroll
    for (int r = 0; r < 4; ++r)
      ar[r] = __shfl(alpha, (lane & 48) | (g * 4 + r), 64);
#pragma unroll
    for (int fd = 0; fd < 4; ++fd)
#pragma unroll
      for (int r = 0; r < 4; ++r) acc[fd][r] *= ar[r];

    // ---- P -> LDS (per-wave buffer): lane owns P[q=c][keys f*16+4g+0..3]
#pragma unroll
    for (int f = 0; f < 4; ++f) {
      short4v pk = { f2bf(sc[f][0]), f2bf(sc[f][1]),
                     f2bf(sc[f][2]), f2bf(sc[f][3]) };
      *(short4v*)&p_lds[w][c][f * 16 + 4 * g] = pk;
    }

    // ---- O += P V
#pragma unroll
    for (int ks = 0; ks < 2; ++ks) {
      bf16x8 pa = *(const bf16x8*)&p_lds[w][c][ks * 32 + g * 8];
#pragma unroll
      for (int fd = 0; fd < 4; ++fd) {
        bf16x8 vb = *(const bf16x8*)&vt_lds[cur][fd * 16 + c][ks * 32 + g * 8];
        acc[fd] = __builtin_amdgcn_mfma_f32_16x16x32_bf16(pa, vb, acc[fd], 0, 0, 0);
      }
    }

    // ---- stage next tile into the idle buffer (cvt+write from held regs);
    //      ONE barrier flips it
    if (has_next) write_kv(cur ^ 1);
    __syncthreads();
  };

  for (int tt = 0; tt < NKV; tt += 2) {
    body(tt,     mA, tt + 2 < NKV);   // consume m(tt),   refill -> m(tt+2)
    body(tt + 1, mB, tt + 3 < NKV);   // consume m(tt+1), refill -> m(tt+3)
  }

  // ---- epilogue: acc[fd][r] = O[q=g*4+r][d=fd*16+c]; l lives at lane c'=q
  const float li = 1.0f / l_run;
  float lr[4];
#pragma unroll
  for (int r = 0; r < 4; ++r)
    lr[r] = __shfl(li, (lane & 48) | (g * 4 + r), 64);
  float* orow = O + ((size_t)b * L_ + q0 + w * 16 + g * 4) * D_;
#pragma unroll
  for (int fd = 0; fd < 4; ++fd)
#pragma unroll
    for (int r = 0; r < 4; ++r)
      orow[(size_t)r * D_ + fd * 16 + c] = acc[fd][r] * lr[r];
}

extern "C" void kernel_launch(void* const* d_in, const int* in_sizes, int n_in,
                              void* d_out, int out_size, void* d_ws, size_t ws_size,
                              hipStream_t stream) {
  const float* q = (const float*)d_in[0];
  const float* k = (const float*)d_in[1];
  const float* v = (const float*)d_in[2];
  const int* m = (const int*)d_in[3]; // jax bool shipped as int32
  float* o = (float*)d_out;
  attn_fwd<<<dim3(512), 512, 0, stream>>>(q, k, v, m, o);
}